// Round 1
// baseline (82.078 us; speedup 1.0000x reference)
//
#include <hip/hip_runtime.h>

#define S_PTS 4096  // sparse point count (fixed by problem)

// Branchless sorted top-3 insert: (b0<=b1<=b2) with indices.
// Evaluation order matters: b2 uses old b1, b1 uses old b0.
#define INSERT3(dv, sv)                                          \
    {                                                            \
        const float _d = (dv); const int _s = (sv);              \
        const bool lt0 = _d < b0, lt1 = _d < b1, lt2 = _d < b2;  \
        b2 = lt1 ? b1 : (lt2 ? _d : b2);                         \
        i2 = lt1 ? i1 : (lt2 ? _s : i2);                         \
        b1 = lt0 ? b0 : (lt1 ? _d : b1);                         \
        i1 = lt0 ? i0 : (lt1 ? _s : i1);                         \
        b0 = lt0 ? _d : b0;                                      \
        i0 = lt0 ? _s : i0;                                      \
    }

// 256 threads = 64 queries x 4 threads/query. LDS = 64 KB -> 2 blocks/CU.
__global__ __launch_bounds__(256, 2)
void upsample_flow_knn3(const float* __restrict__ xyz,         // [B,3,N]
                        const float* __restrict__ sparse_xyz,  // [B,3,S]
                        const float* __restrict__ sparse_flow, // [B,3,S]
                        float* __restrict__ out,               // [B,3,N]
                        int N, int blocks_per_batch)
{
    __shared__ float4 spt[S_PTS];  // (x, y, z, |s|^2)

    const int tid = threadIdx.x;
    const int b   = blockIdx.x / blocks_per_batch;
    const int qb  = blockIdx.x % blocks_per_batch;

    // ---- stage sparse points (+ precomputed squared norm) into LDS ----
    const float* sx = sparse_xyz + (size_t)b * 3 * S_PTS;
    #pragma unroll
    for (int i = tid; i < S_PTS; i += 256) {
        const float px = sx[i];
        const float py = sx[S_PTS + i];
        const float pz = sx[2 * S_PTS + i];
        // match np: (px*px + py*py) + pz*pz, no FMA contraction
        const float sn = __fadd_rn(
            __fadd_rn(__fmul_rn(px, px), __fmul_rn(py, py)),
            __fmul_rn(pz, pz));
        spt[i] = make_float4(px, py, pz, sn);
    }
    __syncthreads();

    const int q = tid >> 2;   // query within block
    const int j = tid & 3;    // scanner lane within query group
    const int n = qb * 64 + q;

    const float* xq = xyz + (size_t)b * 3 * N;
    const float x0 = xq[n];
    const float x1 = xq[N + n];
    const float x2 = xq[2 * N + n];
    const float qn = __fadd_rn(
        __fadd_rn(__fmul_rn(x0, x0), __fmul_rn(x1, x1)),
        __fmul_rn(x2, x2));

    float b0 = 3.4e38f, b1 = 3.4e38f, b2 = 3.4e38f;
    int   i0 = 0, i1 = 0, i2 = 0;

    // ---- scan: thread j handles s = 4*i + j (interleaved, conflict-free) ----
    #pragma unroll 4
    for (int i = 0; i < S_PTS / 4; ++i) {
        const int s = (i << 2) | j;
        const float4 p = spt[s];
        // expanded-form d2, replicating reference op order:
        // d2 = (qn - 2*(x.s)) + sn   with dot = (x0*sx + x1*sy) + x2*sz
        const float dot = __fadd_rn(
            __fadd_rn(__fmul_rn(x0, p.x), __fmul_rn(x1, p.y)),
            __fmul_rn(x2, p.z));
        const float d2 = __fadd_rn(
            __fsub_rn(qn, __fmul_rn(2.0f, dot)), p.w);
        INSERT3(d2, s);
    }

    // ---- merge the 4 partial top-3s (butterfly within wave) ----
    #pragma unroll
    for (int m = 1; m <= 2; m <<= 1) {
        const float c0 = __shfl_xor(b0, m, 64);
        const float c1 = __shfl_xor(b1, m, 64);
        const float c2 = __shfl_xor(b2, m, 64);
        const int   k0 = __shfl_xor(i0, m, 64);
        const int   k1 = __shfl_xor(i1, m, 64);
        const int   k2 = __shfl_xor(i2, m, 64);
        INSERT3(c0, k0);
        INSERT3(c1, k1);
        INSERT3(c2, k2);
    }

    // ---- finalize: weights from direct-diff norm (as reference), gather flow ----
    if (j == 0 && n < N) {
        const float4 p0 = spt[i0];
        const float4 p1 = spt[i1];
        const float4 p2 = spt[i2];

        float dx, dy, dz;
        dx = p0.x - x0; dy = p0.y - x1; dz = p0.z - x2;
        const float dist0 = fmaxf(sqrtf(dx * dx + dy * dy + dz * dz), 1e-10f);
        dx = p1.x - x0; dy = p1.y - x1; dz = p1.z - x2;
        const float dist1 = fmaxf(sqrtf(dx * dx + dy * dy + dz * dz), 1e-10f);
        dx = p2.x - x0; dy = p2.y - x1; dz = p2.z - x2;
        const float dist2 = fmaxf(sqrtf(dx * dx + dy * dy + dz * dz), 1e-10f);

        const float inv0 = 1.0f / dist0;
        const float inv1 = 1.0f / dist1;
        const float inv2 = 1.0f / dist2;
        const float wsum = (inv0 + inv1) + inv2;
        const float w0 = inv0 / wsum;
        const float w1 = inv1 / wsum;
        const float w2 = inv2 / wsum;

        const float* fl = sparse_flow + (size_t)b * 3 * S_PTS;
        float* ob = out + (size_t)b * 3 * N;
        #pragma unroll
        for (int c = 0; c < 3; ++c) {
            const float f0 = fl[c * S_PTS + i0];
            const float f1 = fl[c * S_PTS + i1];
            const float f2 = fl[c * S_PTS + i2];
            ob[c * N + n] = (w0 * f0 + w1 * f1) + w2 * f2;
        }
    }
}

extern "C" void kernel_launch(void* const* d_in, const int* in_sizes, int n_in,
                              void* d_out, int out_size, void* d_ws, size_t ws_size,
                              hipStream_t stream)
{
    const float* xyz         = (const float*)d_in[0];
    const float* sparse_xyz  = (const float*)d_in[1];
    const float* sparse_flow = (const float*)d_in[2];
    float* out = (float*)d_out;

    const int B = in_sizes[1] / (3 * S_PTS);      // 2
    const int N = in_sizes[0] / (3 * B);          // 16384
    const int blocks_per_batch = (N + 63) / 64;   // 256

    dim3 grid(B * blocks_per_batch);
    dim3 block(256);
    upsample_flow_knn3<<<grid, block, 0, stream>>>(
        xyz, sparse_xyz, sparse_flow, out, N, blocks_per_batch);
}

// Round 2
// 77.690 us; speedup vs baseline: 1.0565x; 1.0565x over previous
//
#include <hip/hip_runtime.h>

#define S_PTS 4096  // sparse point count (fixed by problem)

// Full sorted top-3 insert (used in the cross-lane merge where d may be >= b2).
__device__ __forceinline__ void insert3_full(float d, int s,
    float& b0, float& b1, float& b2, int& i0, int& i1, int& i2)
{
    const bool lt0 = d < b0, lt1 = d < b1, lt2 = d < b2;
    b2 = lt1 ? b1 : (lt2 ? d : b2);
    i2 = lt1 ? i1 : (lt2 ? s : i2);
    b1 = lt0 ? b0 : (lt1 ? d : b1);
    i1 = lt0 ? i0 : (lt1 ? s : i1);
    b0 = lt0 ? d : b0;
    i0 = lt0 ? s : i0;
}

// Guarded insert: caller guarantees d < b2 (10 ops instead of 15).
__device__ __forceinline__ void insert3_hit(float d, int s,
    float& b0, float& b1, float& b2, int& i0, int& i1, int& i2)
{
    const bool lt0 = d < b0, lt1 = d < b1;
    b2 = lt1 ? b1 : d;
    i2 = lt1 ? i1 : s;
    b1 = lt0 ? b0 : (lt1 ? d : b1);
    i1 = lt0 ? i0 : (lt1 ? s : i1);
    b0 = lt0 ? d : b0;
    i0 = lt0 ? s : i0;
}

// Finalize one query: weights from direct-diff norm (matches reference),
// gather flow, write 3 channels. Identical math to the round-1 passing kernel.
__device__ __forceinline__ void finalize_query(
    const float4* __restrict__ spt, const float* __restrict__ fl,
    float* __restrict__ ob, int N, int n,
    float x0, float x1, float x2, int i0, int i1, int i2)
{
    const float4 p0 = spt[i0];
    const float4 p1 = spt[i1];
    const float4 p2 = spt[i2];

    float dx, dy, dz;
    dx = p0.x - x0; dy = p0.y - x1; dz = p0.z - x2;
    const float dist0 = fmaxf(sqrtf(dx * dx + dy * dy + dz * dz), 1e-10f);
    dx = p1.x - x0; dy = p1.y - x1; dz = p1.z - x2;
    const float dist1 = fmaxf(sqrtf(dx * dx + dy * dy + dz * dz), 1e-10f);
    dx = p2.x - x0; dy = p2.y - x1; dz = p2.z - x2;
    const float dist2 = fmaxf(sqrtf(dx * dx + dy * dy + dz * dz), 1e-10f);

    const float inv0 = 1.0f / dist0;
    const float inv1 = 1.0f / dist1;
    const float inv2 = 1.0f / dist2;
    const float wsum = (inv0 + inv1) + inv2;
    const float w0 = inv0 / wsum;
    const float w1 = inv1 / wsum;
    const float w2 = inv2 / wsum;

    #pragma unroll
    for (int c = 0; c < 3; ++c) {
        const float f0 = fl[c * S_PTS + i0];
        const float f1 = fl[c * S_PTS + i1];
        const float f2 = fl[c * S_PTS + i2];
        ob[c * N + n] = (w0 * f0 + w1 * f1) + w2 * f2;
    }
}

// 256 threads = 32 query-groups x 8 scanner lanes; each lane owns R=2 queries.
// 64 queries/block. LDS = 64 KB -> 2 blocks/CU (8 waves/CU).
__global__ __launch_bounds__(256, 2)
void upsample_flow_knn3(const float* __restrict__ xyz,         // [B,3,N]
                        const float* __restrict__ sparse_xyz,  // [B,3,S]
                        const float* __restrict__ sparse_flow, // [B,3,S]
                        float* __restrict__ out,               // [B,3,N]
                        int N, int blocks_per_batch)
{
    __shared__ float4 spt[S_PTS];  // (x, y, z, |s|^2)

    const int tid = threadIdx.x;
    const int b   = blockIdx.x / blocks_per_batch;
    const int qb  = blockIdx.x % blocks_per_batch;

    // ---- stage sparse points (+ precomputed squared norm) into LDS ----
    const float* sx = sparse_xyz + (size_t)b * 3 * S_PTS;
    for (int i = tid; i < S_PTS; i += 256) {
        const float px = sx[i];
        const float py = sx[S_PTS + i];
        const float pz = sx[2 * S_PTS + i];
        // match np: (px*px + py*py) + pz*pz, no FMA contraction
        const float sn = __fadd_rn(
            __fadd_rn(__fmul_rn(px, px), __fmul_rn(py, py)),
            __fmul_rn(pz, pz));
        spt[i] = make_float4(px, py, pz, sn);
    }
    __syncthreads();

    const int g = tid >> 3;   // query group within block (0..31)
    const int j = tid & 7;    // scanner lane within group (0..7)
    const int nA = qb * 64 + g;
    const int nB = nA + 32;

    const float* xq = xyz + (size_t)b * 3 * N;
    const float xA0 = xq[nA];
    const float xA1 = xq[N + nA];
    const float xA2 = xq[2 * N + nA];
    const float qnA = __fadd_rn(
        __fadd_rn(__fmul_rn(xA0, xA0), __fmul_rn(xA1, xA1)),
        __fmul_rn(xA2, xA2));
    const float xB0 = xq[nB];
    const float xB1 = xq[N + nB];
    const float xB2 = xq[2 * N + nB];
    const float qnB = __fadd_rn(
        __fadd_rn(__fmul_rn(xB0, xB0), __fmul_rn(xB1, xB1)),
        __fmul_rn(xB2, xB2));

    float a0 = 3.4e38f, a1 = 3.4e38f, a2 = 3.4e38f;
    int  ia0 = 0, ia1 = 0, ia2 = 0;
    float c0 = 3.4e38f, c1 = 3.4e38f, c2 = 3.4e38f;
    int  ib0 = 0, ib1 = 0, ib2 = 0;

    // ---- scan: lane j handles s = 8*i + j; one LDS read feeds 2 queries ----
    #pragma unroll 4
    for (int i = 0; i < S_PTS / 8; ++i) {
        const int s = (i << 3) | j;
        const float4 p = spt[s];

        // expanded-form d2, same op order as round-1 passing kernel:
        // d2 = (qn - 2*dot) + sn,  dot = (x0*px + x1*py) + x2*pz
        const float dotA = __fadd_rn(
            __fadd_rn(__fmul_rn(xA0, p.x), __fmul_rn(xA1, p.y)),
            __fmul_rn(xA2, p.z));
        const float d2A = __fadd_rn(
            __fsub_rn(qnA, __fmul_rn(2.0f, dotA)), p.w);
        if (d2A < a2)
            insert3_hit(d2A, s, a0, a1, a2, ia0, ia1, ia2);

        const float dotB = __fadd_rn(
            __fadd_rn(__fmul_rn(xB0, p.x), __fmul_rn(xB1, p.y)),
            __fmul_rn(xB2, p.z));
        const float d2B = __fadd_rn(
            __fsub_rn(qnB, __fmul_rn(2.0f, dotB)), p.w);
        if (d2B < c2)
            insert3_hit(d2B, s, c0, c1, c2, ib0, ib1, ib2);
    }

    // ---- merge the 8 partial top-3s per query (butterfly within group) ----
    #pragma unroll
    for (int m = 1; m <= 4; m <<= 1) {
        const float ra0 = __shfl_xor(a0, m, 64);
        const float ra1 = __shfl_xor(a1, m, 64);
        const float ra2 = __shfl_xor(a2, m, 64);
        const int   ka0 = __shfl_xor(ia0, m, 64);
        const int   ka1 = __shfl_xor(ia1, m, 64);
        const int   ka2 = __shfl_xor(ia2, m, 64);
        insert3_full(ra0, ka0, a0, a1, a2, ia0, ia1, ia2);
        insert3_full(ra1, ka1, a0, a1, a2, ia0, ia1, ia2);
        insert3_full(ra2, ka2, a0, a1, a2, ia0, ia1, ia2);

        const float rb0 = __shfl_xor(c0, m, 64);
        const float rb1 = __shfl_xor(c1, m, 64);
        const float rb2 = __shfl_xor(c2, m, 64);
        const int   kb0 = __shfl_xor(ib0, m, 64);
        const int   kb1 = __shfl_xor(ib1, m, 64);
        const int   kb2 = __shfl_xor(ib2, m, 64);
        insert3_full(rb0, kb0, c0, c1, c2, ib0, ib1, ib2);
        insert3_full(rb1, kb1, c0, c1, c2, ib0, ib1, ib2);
        insert3_full(rb2, kb2, c0, c1, c2, ib0, ib1, ib2);
    }

    // ---- finalize both queries on lane j==0 ----
    if (j == 0) {
        const float* fl = sparse_flow + (size_t)b * 3 * S_PTS;
        float* ob = out + (size_t)b * 3 * N;
        if (nA < N)
            finalize_query(spt, fl, ob, N, nA, xA0, xA1, xA2, ia0, ia1, ia2);
        if (nB < N)
            finalize_query(spt, fl, ob, N, nB, xB0, xB1, xB2, ib0, ib1, ib2);
    }
}

extern "C" void kernel_launch(void* const* d_in, const int* in_sizes, int n_in,
                              void* d_out, int out_size, void* d_ws, size_t ws_size,
                              hipStream_t stream)
{
    const float* xyz         = (const float*)d_in[0];
    const float* sparse_xyz  = (const float*)d_in[1];
    const float* sparse_flow = (const float*)d_in[2];
    float* out = (float*)d_out;

    const int B = in_sizes[1] / (3 * S_PTS);      // 2
    const int N = in_sizes[0] / (3 * B);          // 16384
    const int blocks_per_batch = (N + 63) / 64;   // 256

    dim3 grid(B * blocks_per_batch);
    dim3 block(256);
    upsample_flow_knn3<<<grid, block, 0, stream>>>(
        xyz, sparse_xyz, sparse_flow, out, N, blocks_per_batch);
}